// Round 1
// baseline (1422.090 us; speedup 1.0000x reference)
//
#include <hip/hip_runtime.h>
#include <cmath>

#define HW   256
#define NPIX 65536   // 256*256
#define CIN  64
#define C2   340
#define HID  170

// Orthonormal DCT-II basis for n=8 as compile-time constants (fold into FMAs).
#define A0 0.35355339059327373f
#define A1 0.49039264020161522f
#define A2 0.46193976625564337f
#define A3 0.41573480615127262f
#define A4 0.35355339059327379f
#define A5 0.27778511650980114f
#define A6 0.19134171618254492f
#define A7 0.09754516100806417f

__device__ static constexpr float MD[8][8] = {
    { A0,  A0,  A0,  A0,  A0,  A0,  A0,  A0},
    { A1,  A3,  A5,  A7, -A7, -A5, -A3, -A1},
    { A2,  A6, -A6, -A2, -A2, -A6,  A6,  A2},
    { A3, -A7, -A1, -A5,  A5,  A1,  A7, -A3},
    { A4, -A4, -A4,  A4,  A4, -A4, -A4,  A4},
    { A5, -A1,  A7,  A3, -A3, -A7,  A1, -A5},
    { A6, -A2,  A2, -A6, -A6,  A2, -A2,  A6},
    { A7, -A5,  A3, -A1,  A1, -A3,  A5, -A7},
};

// ---------------------------------------------------------------------------
// Kernel A: project_in (1x1 conv) + DCT + quant + IDCT, writes yr.
// Grid: (256 tiles, nb batches), block 256.  Tile = 16x16 px = 2x2 patches.
// ---------------------------------------------------------------------------
__global__ __launch_bounds__(256) void kA(
    const float* __restrict__ x,      // [nb][64][256][256]
    const float* __restrict__ Win,    // [340][64]
    const float* __restrict__ quant,  // [340][8][8]
    float* __restrict__ yr)           // [nb][340][256][256]
{
    const int tid  = threadIdx.x;
    const int tile = blockIdx.x;
    const int bb   = blockIdx.y;
    const int ty = tile >> 4, tx = tile & 15;
    const int r  = tid >> 4,  c  = tid & 15;

    // Per-pixel role: load all 64 input channels into registers.
    const float* xp = x + (size_t)bb * (CIN * NPIX) + (ty * 16 + r) * HW + (tx * 16 + c);
    float xr[64];
#pragma unroll
    for (int ic = 0; ic < 64; ++ic) xr[ic] = xp[(size_t)ic * NPIX];

    __shared__ float yb[8][16][20];   // [ch][row16][col16 + pad]

    // DCT-role indices: thread <-> (channel-of-chunk, patch, row/col lane)
    const int ch  = tid >> 5;         // 0..7
    const int pat = (tid >> 3) & 3;   // 0..3  (2x2 patches)
    const int lan = tid & 7;          // 0..7
    const int pr8 = (pat >> 1) * 8;   // patch row offset in tile
    const int pc8 = (pat & 1) * 8;    // patch col offset in tile

#pragma unroll 1
    for (int chunk = 0; chunk < 43; ++chunk) {
        const int oc0 = chunk * 8;

        // ---- project_in: acc[j] = sum_ic Win[oc0+j][ic] * xr[ic] ----
        const float* wrow[8];
#pragma unroll
        for (int j = 0; j < 8; ++j) {
            int oc = oc0 + j; if (oc > C2 - 1) oc = C2 - 1;   // clamp tail chunk
            wrow[j] = Win + oc * 64;
        }
        float acc[8];
#pragma unroll
        for (int j = 0; j < 8; ++j) acc[j] = 0.f;
#pragma unroll 4
        for (int ic = 0; ic < 64; ++ic) {
            const float xv = xr[ic];
#pragma unroll
            for (int j = 0; j < 8; ++j) acc[j] = fmaf(wrow[j][ic], xv, acc[j]);
        }

        __syncthreads();   // previous chunk finished reading yb
#pragma unroll
        for (int j = 0; j < 8; ++j) yb[j][r][c] = acc[j];
        __syncthreads();

        // ---- Pass R1 (rows): A = X * M^T : out[j] = sum_q v[q] * MD[j][q]
        {
            float v[8], o[8];
#pragma unroll
            for (int q = 0; q < 8; ++q) v[q] = yb[ch][pr8 + lan][pc8 + q];
#pragma unroll
            for (int j = 0; j < 8; ++j) {
                float s = v[0] * MD[j][0];
#pragma unroll
                for (int q = 1; q < 8; ++q) s = fmaf(v[q], MD[j][q], s);
                o[j] = s;
            }
#pragma unroll
            for (int j = 0; j < 8; ++j) yb[ch][pr8 + lan][pc8 + j] = o[j];
        }
        __syncthreads();

        // ---- Pass C (cols): d = M v ; d *= quant ; e = M^T d  (one round-trip)
        {
            float v[8], d[8], e[8];
#pragma unroll
            for (int i = 0; i < 8; ++i) v[i] = yb[ch][pr8 + i][pc8 + lan];
            int ocq = oc0 + ch; if (ocq > C2 - 1) ocq = C2 - 1;
            const float* qp = quant + ocq * 64 + lan;
#pragma unroll
            for (int i = 0; i < 8; ++i) {
                float s = v[0] * MD[i][0];
#pragma unroll
                for (int p = 1; p < 8; ++p) s = fmaf(v[p], MD[i][p], s);
                d[i] = s * qp[i * 8];
            }
#pragma unroll
            for (int p = 0; p < 8; ++p) {
                float s = d[0] * MD[0][p];
#pragma unroll
                for (int i = 1; i < 8; ++i) s = fmaf(d[i], MD[i][p], s);
                e[p] = s;
            }
#pragma unroll
            for (int i = 0; i < 8; ++i) yb[ch][pr8 + i][pc8 + lan] = e[i];
        }
        __syncthreads();

        // ---- Pass R2 (rows): Y = E * M : out[q] = sum_j v[j] * MD[j][q] -> global
        {
            const int oc = oc0 + ch;
            float v[8], o[8];
#pragma unroll
            for (int j = 0; j < 8; ++j) v[j] = yb[ch][pr8 + lan][pc8 + j];
#pragma unroll
            for (int q = 0; q < 8; ++q) {
                float s = v[0] * MD[0][q];
#pragma unroll
                for (int j = 1; j < 8; ++j) s = fmaf(v[j], MD[j][q], s);
                o[q] = s;
            }
            if (oc < C2) {
                float4* dst = (float4*)(yr + (size_t)(bb * C2 + oc) * NPIX
                                        + (ty * 16 + pr8 + lan) * HW + tx * 16 + pc8);
                dst[0] = make_float4(o[0], o[1], o[2], o[3]);
                dst[1] = make_float4(o[4], o[5], o[6], o[7]);
            }
        }
    }
}

// ---------------------------------------------------------------------------
// Kernel B: depthwise 3x3 (zero pad) + exact gelu gate + project_out.
// Grid: (256 tiles, nb batches), block 256.
// ---------------------------------------------------------------------------
__global__ __launch_bounds__(256) void kB(
    const float* __restrict__ yr,     // [nb][340][256][256]
    const float* __restrict__ Wdw,    // [340][3][3]
    const float* __restrict__ WoutT,  // [170][64]
    float* __restrict__ out)          // [nb][64][256][256]
{
    const int tid  = threadIdx.x;
    const int tile = blockIdx.x;
    const int bb   = blockIdx.y;
    const int ty = tile >> 4, tx = tile & 15;
    const int r  = tid >> 4,  c  = tid & 15;

    __shared__ float t1[18][20];
    __shared__ float t2[18][20];

    float acc[64];
#pragma unroll
    for (int o = 0; o < 64; ++o) acc[o] = 0.f;

    const size_t base = (size_t)bb * C2 * NPIX;

#pragma unroll 1
    for (int h = 0; h < HID; ++h) {
        __syncthreads();   // previous iteration done reading t1/t2
        // stage 18x18 halo tiles for channels h and h+170 (zero-pad at borders)
#pragma unroll
        for (int k = 0; k < 3; ++k) {
            const int i = tid + k * 256;
            if (i < 648) {
                const int bsel = (i >= 324);
                const int idx  = i - bsel * 324;
                const int lr   = idx / 18;
                const int lc   = idx - lr * 18;
                const int gy   = ty * 16 + lr - 1;
                const int gx   = tx * 16 + lc - 1;
                float v = 0.f;
                if (gy >= 0 && gy < HW && gx >= 0 && gx < HW)
                    v = yr[base + (size_t)(h + bsel * HID) * NPIX + gy * HW + gx];
                float* tp = bsel ? &t2[0][0] : &t1[0][0];
                tp[lr * 20 + lc] = v;
            }
        }
        __syncthreads();

        const float* w1 = Wdw + (size_t)h * 9;
        const float* w2 = Wdw + (size_t)(h + HID) * 9;
        float s1 = 0.f, s2 = 0.f;
#pragma unroll
        for (int dy = 0; dy < 3; ++dy)
#pragma unroll
            for (int dx = 0; dx < 3; ++dx) {
                s1 = fmaf(t1[r + dy][c + dx], w1[dy * 3 + dx], s1);
                s2 = fmaf(t2[r + dy][c + dx], w2[dy * 3 + dx], s2);
            }
        // exact gelu: 0.5*x*(1+erf(x/sqrt(2)))
        const float g = 0.5f * s1 * (1.f + erff(s1 * 0.70710678118654752f)) * s2;

        const float* wo = WoutT + h * 64;
#pragma unroll
        for (int o = 0; o < 64; ++o) acc[o] = fmaf(wo[o], g, acc[o]);
    }

    float* op = out + (size_t)bb * CIN * NPIX + (ty * 16 + r) * HW + tx * 16 + c;
#pragma unroll
    for (int o = 0; o < 64; ++o) op[(size_t)o * NPIX] = acc[o];
}

// Transpose W_out [64][170] -> WoutT [170][64] so kernel B's weight reads are
// contiguous scalar loads.
__global__ __launch_bounds__(256) void kT(const float* __restrict__ Wout,
                                          float* __restrict__ WoutT)
{
    const int i = blockIdx.x * 256 + threadIdx.x;
    if (i < 64 * 170) {
        const int o = i / 170;
        const int h = i - o * 170;
        WoutT[h * 64 + o] = Wout[i];
    }
}

extern "C" void kernel_launch(void* const* d_in, const int* in_sizes, int n_in,
                              void* d_out, int out_size, void* d_ws, size_t ws_size,
                              hipStream_t stream)
{
    const float* x     = (const float*)d_in[0];
    const float* Win   = (const float*)d_in[1];
    const float* Wdw   = (const float*)d_in[2];
    const float* quant = (const float*)d_in[3];
    const float* Wout  = (const float*)d_in[4];
    float* out = (float*)d_out;

    float* WoutT = (float*)d_ws;                   // 170*64*4 = 43.5 KB
    float* yr    = (float*)d_ws + (65536 / 4);     // yr after 64 KB

    const size_t perBatch = (size_t)C2 * NPIX * sizeof(float);   // 89.1 MB
    const size_t avail = ws_size > 65536 ? ws_size - 65536 : 0;
    int nb = 1;
    if (avail >= 4 * perBatch)      nb = 4;
    else if (avail >= 2 * perBatch) nb = 2;

    kT<<<43, 256, 0, stream>>>(Wout, WoutT);

    for (int b0 = 0; b0 < 4; b0 += nb) {
        dim3 grid(256, nb);
        kA<<<grid, 256, 0, stream>>>(x + (size_t)b0 * CIN * NPIX, Win, quant, yr);
        kB<<<grid, 256, 0, stream>>>(yr, Wdw, WoutT, out + (size_t)b0 * CIN * NPIX);
    }
}

// Round 2
// 806.580 us; speedup vs baseline: 1.7631x; 1.7631x over previous
//
#include <hip/hip_runtime.h>
#include <cmath>

#define HW   256
#define NPIX 65536   // 256*256
#define CIN  64
#define C2   340
#define HID  170

// Orthonormal DCT-II basis for n=8 as compile-time constants (fold into FMAs).
#define A0 0.35355339059327373f
#define A1 0.49039264020161522f
#define A2 0.46193976625564337f
#define A3 0.41573480615127262f
#define A4 0.35355339059327379f
#define A5 0.27778511650980114f
#define A6 0.19134171618254492f
#define A7 0.09754516100806417f

__device__ static constexpr float MD[8][8] = {
    { A0,  A0,  A0,  A0,  A0,  A0,  A0,  A0},
    { A1,  A3,  A5,  A7, -A7, -A5, -A3, -A1},
    { A2,  A6, -A6, -A2, -A2, -A6,  A6,  A2},
    { A3, -A7, -A1, -A5,  A5,  A1,  A7, -A3},
    { A4, -A4, -A4,  A4,  A4, -A4, -A4,  A4},
    { A5, -A1,  A7,  A3, -A3, -A7,  A1, -A5},
    { A6, -A2,  A2, -A6, -A6,  A2, -A2,  A6},
    { A7, -A5,  A3, -A1,  A1, -A3,  A5, -A7},
};

// ---------------------------------------------------------------------------
// Kernel A: project_in (1x1 conv) + DCT + quant + IDCT, writes yr (fp16).
// Grid: (256 tiles, nb batches), block 256.  Tile = 16x16 px = 2x2 patches.
// ---------------------------------------------------------------------------
__global__ __launch_bounds__(256) void kA(
    const float* __restrict__ x,      // [nb][64][256][256]
    const float* __restrict__ Win,    // [340][64]
    const float* __restrict__ quant,  // [340][8][8]
    _Float16* __restrict__ yr)        // [nb][340][256][256] fp16
{
    const int tid  = threadIdx.x;
    const int tile = blockIdx.x;
    const int bb   = blockIdx.y;
    const int ty = tile >> 4, tx = tile & 15;
    const int r  = tid >> 4,  c  = tid & 15;

    // Per-pixel role: all 64 input channels in registers (FULLY static indexing
    // everywhere below so the array is never demoted to scratch).
    const float* xp = x + (size_t)bb * (CIN * NPIX) + (ty * 16 + r) * HW + (tx * 16 + c);
    float xr[64];
#pragma unroll
    for (int ic = 0; ic < 64; ++ic) xr[ic] = xp[(size_t)ic * NPIX];

    __shared__ float yb[8][16][20];   // [ch][row16][col16 + pad]

    // DCT-role indices: thread <-> (channel-of-chunk, patch, row/col lane)
    const int ch  = tid >> 5;         // 0..7
    const int pat = (tid >> 3) & 3;   // 0..3  (2x2 patches)
    const int lan = tid & 7;          // 0..7
    const int pr8 = (pat >> 1) * 8;
    const int pc8 = (pat & 1) * 8;

#pragma unroll 1
    for (int chunk = 0; chunk < 43; ++chunk) {
        const int oc0 = chunk * 8;

        // ---- project_in: acc[j] = sum_ic Win[oc0+j][ic] * xr[ic] ----
        float acc[8];
#pragma unroll
        for (int j = 0; j < 8; ++j) {
            int oc = oc0 + j; if (oc > C2 - 1) oc = C2 - 1;   // clamp tail chunk
            const float* wr = Win + oc * 64;                  // wave-uniform -> s_load
            float s = 0.f;
#pragma unroll
            for (int ic = 0; ic < 64; ++ic) s = fmaf(wr[ic], xr[ic], s);
            acc[j] = s;
        }

        __syncthreads();   // previous chunk finished reading yb
#pragma unroll
        for (int j = 0; j < 8; ++j) yb[j][r][c] = acc[j];
        __syncthreads();

        // ---- Pass R1 (rows): out[j] = sum_q v[q] * MD[j][q]
        {
            float v[8], o[8];
#pragma unroll
            for (int q = 0; q < 8; ++q) v[q] = yb[ch][pr8 + lan][pc8 + q];
#pragma unroll
            for (int j = 0; j < 8; ++j) {
                float s = v[0] * MD[j][0];
#pragma unroll
                for (int q = 1; q < 8; ++q) s = fmaf(v[q], MD[j][q], s);
                o[j] = s;
            }
#pragma unroll
            for (int j = 0; j < 8; ++j) yb[ch][pr8 + lan][pc8 + j] = o[j];
        }
        __syncthreads();

        // ---- Pass C (cols): d = M v ; d *= quant ; e = M^T d
        {
            float v[8], d[8], e[8];
#pragma unroll
            for (int i = 0; i < 8; ++i) v[i] = yb[ch][pr8 + i][pc8 + lan];
            int ocq = oc0 + ch; if (ocq > C2 - 1) ocq = C2 - 1;
            const float* qp = quant + ocq * 64 + lan;
#pragma unroll
            for (int i = 0; i < 8; ++i) {
                float s = v[0] * MD[i][0];
#pragma unroll
                for (int p = 1; p < 8; ++p) s = fmaf(v[p], MD[i][p], s);
                d[i] = s * qp[i * 8];
            }
#pragma unroll
            for (int p = 0; p < 8; ++p) {
                float s = d[0] * MD[0][p];
#pragma unroll
                for (int i = 1; i < 8; ++i) s = fmaf(d[i], MD[i][p], s);
                e[p] = s;
            }
#pragma unroll
            for (int i = 0; i < 8; ++i) yb[ch][pr8 + i][pc8 + lan] = e[i];
        }
        __syncthreads();

        // ---- Pass R2 (rows): out[q] = sum_j v[j] * MD[j][q] -> global (fp16)
        {
            const int oc = oc0 + ch;
            float v[8];
#pragma unroll
            for (int j = 0; j < 8; ++j) v[j] = yb[ch][pr8 + lan][pc8 + j];
            union { _Float16 h[8]; float4 f; } u;
#pragma unroll
            for (int q = 0; q < 8; ++q) {
                float s = v[0] * MD[0][q];
#pragma unroll
                for (int j = 1; j < 8; ++j) s = fmaf(v[j], MD[j][q], s);
                u.h[q] = (_Float16)s;
            }
            if (oc < C2) {
                float4* dst = (float4*)(yr + (size_t)(bb * C2 + oc) * NPIX
                                        + (ty * 16 + pr8 + lan) * HW + tx * 16 + pc8);
                *dst = u.f;
            }
        }
    }
}

// ---------------------------------------------------------------------------
// Kernel B: depthwise 3x3 (zero pad) + exact gelu gate + project_out.
// Double-buffered LDS staging, ONE barrier per channel iteration.
// Grid: (256 tiles, nb batches), block 256.
// ---------------------------------------------------------------------------
__global__ __launch_bounds__(256) void kB(
    const _Float16* __restrict__ yr,  // [nb][340][256][256] fp16
    const float* __restrict__ Wdw,    // [340][3][3]
    const float* __restrict__ WoutT,  // [170][64]
    float* __restrict__ out)          // [nb][64][256][256]
{
    const int tid  = threadIdx.x;
    const int tile = blockIdx.x;
    const int bb   = blockIdx.y;
    const int ty = tile >> 4, tx = tile & 15;
    const int r  = tid >> 4,  c  = tid & 15;

    __shared__ float buf[2][720];     // [dbuf][2ch x 18 x 20]

    const _Float16* ybase = yr + (size_t)bb * C2 * NPIX;

    // Precompute the (up to 3) staging slots this thread owns.
    bool   okk[3], inb[3];
    int    ldsoff[3], csel[3];
    int    goff[3];
#pragma unroll
    for (int k = 0; k < 3; ++k) {
        const int i = tid + k * 256;
        okk[k] = (i < 648);
        const int bsel = (i >= 324) ? 1 : 0;
        const int idx = i - bsel * 324;
        const int lr = idx / 18;
        const int lc = idx - lr * 18;
        const int gy = ty * 16 + lr - 1;
        const int gx = tx * 16 + lc - 1;
        inb[k] = okk[k] && gy >= 0 && gy < HW && gx >= 0 && gx < HW;
        ldsoff[k] = bsel * 360 + lr * 20 + lc;
        csel[k]  = bsel * HID;
        goff[k]  = inb[k] ? (gy * HW + gx) : 0;
    }

    float acc[64];
#pragma unroll
    for (int o = 0; o < 64; ++o) acc[o] = 0.f;

    // Prologue: stage h=0 into buf[0].
    {
        float r0[3];
#pragma unroll
        for (int k = 0; k < 3; ++k)
            r0[k] = inb[k] ? (float)ybase[(size_t)csel[k] * NPIX + goff[k]] : 0.f;
#pragma unroll
        for (int k = 0; k < 3; ++k)
            if (okk[k]) buf[0][ldsoff[k]] = r0[k];
    }
    __syncthreads();

#pragma unroll 1
    for (int h = 0; h < HID; ++h) {
        const int cur = h & 1, nxt = cur ^ 1;
        const bool more = (h + 1 < HID);

        // Prefetch next channel pair into registers (latency overlaps compute).
        float rn[3];
        if (more) {
#pragma unroll
            for (int k = 0; k < 3; ++k)
                rn[k] = inb[k] ? (float)ybase[(size_t)(h + 1 + csel[k]) * NPIX + goff[k]] : 0.f;
        }

        // Compute from current buffer.
        const float* w1 = Wdw + (size_t)h * 9;
        const float* w2 = Wdw + (size_t)(h + HID) * 9;
        const float* t  = &buf[cur][0];
        float s1 = 0.f, s2 = 0.f;
#pragma unroll
        for (int dy = 0; dy < 3; ++dy)
#pragma unroll
            for (int dx = 0; dx < 3; ++dx) {
                const int off = (r + dy) * 20 + (c + dx);
                s1 = fmaf(t[off],       w1[dy * 3 + dx], s1);
                s2 = fmaf(t[360 + off], w2[dy * 3 + dx], s2);
            }
        const float g = 0.5f * s1 * (1.f + erff(s1 * 0.70710678118654752f)) * s2;

        const float* wo = WoutT + h * 64;
#pragma unroll
        for (int o = 0; o < 64; ++o) acc[o] = fmaf(wo[o], g, acc[o]);

        // Publish next buffer; single barrier per iteration.
        if (more) {
#pragma unroll
            for (int k = 0; k < 3; ++k)
                if (okk[k]) buf[nxt][ldsoff[k]] = rn[k];
            __syncthreads();
        }
    }

    float* op = out + (size_t)bb * CIN * NPIX + (ty * 16 + r) * HW + tx * 16 + c;
#pragma unroll
    for (int o = 0; o < 64; ++o) op[(size_t)o * NPIX] = acc[o];
}

// Transpose W_out [64][170] -> WoutT [170][64].
__global__ __launch_bounds__(256) void kT(const float* __restrict__ Wout,
                                          float* __restrict__ WoutT)
{
    const int i = blockIdx.x * 256 + threadIdx.x;
    if (i < 64 * 170) {
        const int o = i / 170;
        const int h = i - o * 170;
        WoutT[h * 64 + o] = Wout[i];
    }
}

extern "C" void kernel_launch(void* const* d_in, const int* in_sizes, int n_in,
                              void* d_out, int out_size, void* d_ws, size_t ws_size,
                              hipStream_t stream)
{
    const float* x     = (const float*)d_in[0];
    const float* Win   = (const float*)d_in[1];
    const float* Wdw   = (const float*)d_in[2];
    const float* quant = (const float*)d_in[3];
    const float* Wout  = (const float*)d_in[4];
    float* out = (float*)d_out;

    float*    WoutT = (float*)d_ws;                          // 43.5 KB
    _Float16* yr    = (_Float16*)((char*)d_ws + 65536);      // fp16 yr

    const size_t perBatch = (size_t)C2 * NPIX * sizeof(_Float16);  // 44.56 MB
    const size_t avail = ws_size > 65536 ? ws_size - 65536 : 0;
    int nb = 1;
    if (avail >= 4 * perBatch)      nb = 4;
    else if (avail >= 2 * perBatch) nb = 2;

    kT<<<43, 256, 0, stream>>>(Wout, WoutT);

    for (int b0 = 0; b0 < 4; b0 += nb) {
        dim3 grid(256, nb);
        kA<<<grid, 256, 0, stream>>>(x + (size_t)b0 * CIN * NPIX, Win, quant, yr);
        kB<<<grid, 256, 0, stream>>>(yr, Wdw, WoutT, out + (size_t)b0 * CIN * NPIX);
    }
}

// Round 3
// 591.613 us; speedup vs baseline: 2.4038x; 1.3634x over previous
//
#include <hip/hip_runtime.h>
#include <cmath>

#define HW   256
#define NPIX 65536   // 256*256
#define CIN  64
#define C2   340
#define HID  170

typedef _Float16 f16x8 __attribute__((ext_vector_type(8)));
typedef float    f32x4 __attribute__((ext_vector_type(4)));

// Orthonormal DCT-II basis for n=8 as compile-time constants (fold into FMAs).
#define A0 0.35355339059327373f
#define A1 0.49039264020161522f
#define A2 0.46193976625564337f
#define A3 0.41573480615127262f
#define A4 0.35355339059327379f
#define A5 0.27778511650980114f
#define A6 0.19134171618254492f
#define A7 0.09754516100806417f

__device__ static constexpr float MD[8][8] = {
    { A0,  A0,  A0,  A0,  A0,  A0,  A0,  A0},
    { A1,  A3,  A5,  A7, -A7, -A5, -A3, -A1},
    { A2,  A6, -A6, -A2, -A2, -A6,  A6,  A2},
    { A3, -A7, -A1, -A5,  A5,  A1,  A7, -A3},
    { A4, -A4, -A4,  A4,  A4, -A4, -A4,  A4},
    { A5, -A1,  A7,  A3, -A3, -A7,  A1, -A5},
    { A6, -A2,  A2, -A6, -A6,  A2, -A2,  A6},
    { A7, -A5,  A3, -A1,  A1, -A3,  A5, -A7},
};

// ---------------------------------------------------------------------------
// Prep: convert Win -> fp16 (WinH [340][64]) and Wout -> transposed fp16
// (WoutTH [170][64]).
// ---------------------------------------------------------------------------
__global__ __launch_bounds__(256) void kprep(const float* __restrict__ Win,
                                             const float* __restrict__ Wout,
                                             _Float16* __restrict__ WinH,
                                             _Float16* __restrict__ WoutTH)
{
    const int i = blockIdx.x * 256 + threadIdx.x;
    if (i < C2 * 64) WinH[i] = (_Float16)Win[i];
    const int k = i - C2 * 64;
    if (k >= 0 && k < HID * 64) {
        const int h = k >> 6, o = k & 63;
        WoutTH[k] = (_Float16)Wout[o * HID + h];
    }
}

// ---------------------------------------------------------------------------
// Kernel A: project_in via MFMA (fp16 in, fp32 acc) + VALU DCT/quant/IDCT.
// Block = 256 thr = 4 waves, tile = 16x16 px.  oc processed in 22 chunks of 16.
// ---------------------------------------------------------------------------
__global__ __launch_bounds__(256) void kA(
    const float* __restrict__ x,        // [nb][64][256][256]
    const _Float16* __restrict__ WinH,  // [340][64] fp16
    const float* __restrict__ quant,    // [340][8][8]
    _Float16* __restrict__ yr)          // [nb][340][256][256] fp16
{
    const int tid  = threadIdx.x;
    const int tile = blockIdx.x;
    const int bb   = blockIdx.y;
    const int ty = tile >> 4, tx = tile & 15;
    const int r  = tid >> 4,  c  = tid & 15;
    const int px = tid;                   // pixel id within tile (r*16+c)
    const int wv = tid >> 6;              // wave id 0..3
    const int l  = tid & 63;              // lane
    const int lane15 = l & 15, quad = l >> 4;

    __shared__ _Float16 Ash[256 * 64];    // x tile fp16, XOR-swizzled units
    __shared__ float    Csh[16 * 257];    // 16 oc x 256 px (+1 pad)

    // ---- Stage x tile -> LDS fp16 (each thread stages its own pixel) ----
    const float* xp = x + (size_t)bb * (CIN * NPIX) + (ty * 16 + r) * HW + (tx * 16 + c);
    const int sw = px & 7;
#pragma unroll
    for (int u = 0; u < 8; ++u) {
        union { _Float16 h[8]; f16x8 v; } pk;
#pragma unroll
        for (int j = 0; j < 8; ++j) pk.h[j] = (_Float16)xp[(size_t)(u * 8 + j) * NPIX];
        *(f16x8*)&Ash[px * 64 + ((u ^ sw) * 8)] = pk.v;
    }
    __syncthreads();

    // DCT-role indices
    const int ch  = tid >> 5;             // 0..7
    const int pat = (tid >> 3) & 3;       // 0..3
    const int lan = tid & 7;              // 0..7
    const int pr8 = (pat >> 1) * 8;
    const int pc8 = (pat & 1) * 8;

#pragma unroll 1
    for (int sc = 0; sc < 22; ++sc) {
        // ---- B fragments from global fp16 Win (wave-shared, L1/L2-hot) ----
        const int  oc_n = sc * 16 + lane15;
        const bool ocok = oc_n < C2;
        const int  ocl  = ocok ? oc_n : (C2 - 1);
        f16x8 b0 = *(const f16x8*)(WinH + ocl * 64 + quad * 8);
        f16x8 b1 = *(const f16x8*)(WinH + ocl * 64 + 32 + quad * 8);
        if (!ocok) {
#pragma unroll
            for (int j = 0; j < 8; ++j) { b0[j] = (_Float16)0.f; b1[j] = (_Float16)0.f; }
        }

        // ---- MFMA: C[px, oc16] ; each wave owns 4 px-tiles (rows) ----
#pragma unroll
        for (int tt = 0; tt < 4; ++tt) {
            const int tile16 = wv * 4 + tt;
            const int apx = tile16 * 16 + lane15;
            const int asw = apx & 7;
            f16x8 a0 = *(const f16x8*)&Ash[apx * 64 + ((quad ^ asw) * 8)];
            f16x8 a1 = *(const f16x8*)&Ash[apx * 64 + (((4 + quad) ^ asw) * 8)];
            f32x4 acc = {0.f, 0.f, 0.f, 0.f};
            acc = __builtin_amdgcn_mfma_f32_16x16x32_f16(a0, b0, acc, 0, 0, 0);
            acc = __builtin_amdgcn_mfma_f32_16x16x32_f16(a1, b1, acc, 0, 0, 0);
            // C layout: col = lane&15 (oc), row = quad*4+reg (px within tile)
#pragma unroll
            for (int reg = 0; reg < 4; ++reg)
                Csh[lane15 * 257 + tile16 * 16 + quad * 4 + reg] = acc[reg];
        }
        __syncthreads();

        // ---- Pass R1 (rows): out[j] = sum_q v[q]*MD[j][q], in-place ----
#pragma unroll
        for (int di = 0; di < 2; ++di) {
            float* row = &Csh[(ch + 8 * di) * 257 + (pr8 + lan) * 16 + pc8];
            float v[8], o[8];
#pragma unroll
            for (int q = 0; q < 8; ++q) v[q] = row[q];
#pragma unroll
            for (int j = 0; j < 8; ++j) {
                float s = v[0] * MD[j][0];
#pragma unroll
                for (int q = 1; q < 8; ++q) s = fmaf(v[q], MD[j][q], s);
                o[j] = s;
            }
#pragma unroll
            for (int j = 0; j < 8; ++j) row[j] = o[j];
        }
        __syncthreads();

        // ---- Pass C (cols): d = M v ; d *= quant ; e = M^T d, in-place ----
#pragma unroll
        for (int di = 0; di < 2; ++di) {
            float* colp = &Csh[(ch + 8 * di) * 257 + pr8 * 16 + pc8 + lan];
            float v[8], d[8], e[8];
#pragma unroll
            for (int i = 0; i < 8; ++i) v[i] = colp[i * 16];
            int ocq = sc * 16 + ch + 8 * di; if (ocq > C2 - 1) ocq = C2 - 1;
            const float* qp = quant + ocq * 64 + lan;
#pragma unroll
            for (int i = 0; i < 8; ++i) {
                float s = v[0] * MD[i][0];
#pragma unroll
                for (int p = 1; p < 8; ++p) s = fmaf(v[p], MD[i][p], s);
                d[i] = s * qp[i * 8];
            }
#pragma unroll
            for (int p = 0; p < 8; ++p) {
                float s = d[0] * MD[0][p];
#pragma unroll
                for (int i = 1; i < 8; ++i) s = fmaf(d[i], MD[i][p], s);
                e[p] = s;
            }
#pragma unroll
            for (int i = 0; i < 8; ++i) colp[i * 16] = e[i];
        }
        __syncthreads();

        // ---- Pass R2 (rows): out[q] = sum_j v[j]*MD[j][q] -> global fp16 ----
#pragma unroll
        for (int di = 0; di < 2; ++di) {
            const int oc = sc * 16 + ch + 8 * di;
            const float* row = &Csh[(ch + 8 * di) * 257 + (pr8 + lan) * 16 + pc8];
            float v[8];
#pragma unroll
            for (int j = 0; j < 8; ++j) v[j] = row[j];
            union { _Float16 h[8]; f16x8 f; } u;
#pragma unroll
            for (int q = 0; q < 8; ++q) {
                float s = v[0] * MD[0][q];
#pragma unroll
                for (int j = 1; j < 8; ++j) s = fmaf(v[j], MD[j][q], s);
                u.h[q] = (_Float16)s;
            }
            if (oc < C2) {
                f16x8* dst = (f16x8*)(yr + (size_t)(bb * C2 + oc) * NPIX
                                      + (ty * 16 + pr8 + lan) * HW + tx * 16 + pc8);
                *dst = u.f;
            }
        }
        __syncthreads();
    }
}

// ---------------------------------------------------------------------------
// Kernel B: depthwise 3x3 (zero pad) + exact gelu gate + project_out.
// No LDS, no barriers: 3x3 halo read straight from L1; fp16 Wout weights.
// ---------------------------------------------------------------------------
__global__ __launch_bounds__(256, 4) void kB(
    const _Float16* __restrict__ yr,      // [nb][340][256][256] fp16
    const float* __restrict__ Wdw,        // [340][9]
    const _Float16* __restrict__ WoutTH,  // [170][64] fp16
    float* __restrict__ out)              // [nb][64][256][256]
{
    const int tid  = threadIdx.x;
    const int tile = blockIdx.x;
    const int bb   = blockIdx.y;
    const int ty = tile >> 4, tx = tile & 15;
    const int r  = tid >> 4,  c  = tid & 15;
    const int y0 = ty * 16 + r, x0 = tx * 16 + c;

    const _Float16* pc1 = yr + (size_t)bb * C2 * NPIX + y0 * HW + x0;
    const bool interior = (ty >= 1 && ty <= 14 && tx >= 1 && tx <= 14);

    float acc[64];
#pragma unroll
    for (int o = 0; o < 64; ++o) acc[o] = 0.f;

#pragma unroll 1
    for (int h = 0; h < HID; ++h) {
        const float* w1 = Wdw + (size_t)h * 9;
        const float* w2 = Wdw + (size_t)(h + HID) * 9;
        const _Float16* p1 = pc1 + (size_t)h * NPIX;
        const _Float16* p2 = p1 + (size_t)HID * NPIX;

        float s1 = 0.f, s2 = 0.f;
        if (interior) {
#pragma unroll
            for (int dy = 0; dy < 3; ++dy)
#pragma unroll
                for (int dx = 0; dx < 3; ++dx) {
                    const int off = (dy - 1) * HW + (dx - 1);
                    s1 = fmaf((float)p1[off], w1[dy * 3 + dx], s1);
                    s2 = fmaf((float)p2[off], w2[dy * 3 + dx], s2);
                }
        } else {
#pragma unroll
            for (int dy = 0; dy < 3; ++dy) {
                const int gy = y0 + dy - 1;
#pragma unroll
                for (int dx = 0; dx < 3; ++dx) {
                    const int gx = x0 + dx - 1;
                    const bool ok = ((unsigned)gy < (unsigned)HW) && ((unsigned)gx < (unsigned)HW);
                    const int gyc = gy < 0 ? 0 : (gy > HW - 1 ? HW - 1 : gy);
                    const int gxc = gx < 0 ? 0 : (gx > HW - 1 ? HW - 1 : gx);
                    const int off = (gyc - y0) * HW + (gxc - x0);
                    float v1 = (float)p1[off];
                    float v2 = (float)p2[off];
                    if (!ok) { v1 = 0.f; v2 = 0.f; }
                    s1 = fmaf(v1, w1[dy * 3 + dx], s1);
                    s2 = fmaf(v2, w2[dy * 3 + dx], s2);
                }
            }
        }
        const float g = 0.5f * s1 * (1.f + erff(s1 * 0.70710678118654752f)) * s2;

#pragma unroll
        for (int u = 0; u < 8; ++u) {
            const f16x8 wvv = *(const f16x8*)(WoutTH + h * 64 + u * 8);
#pragma unroll
            for (int j = 0; j < 8; ++j)
                acc[u * 8 + j] = fmaf((float)wvv[j], g, acc[u * 8 + j]);
        }
    }

    float* op = out + (size_t)bb * CIN * NPIX + y0 * HW + x0;
#pragma unroll
    for (int o = 0; o < 64; ++o) op[(size_t)o * NPIX] = acc[o];
}

extern "C" void kernel_launch(void* const* d_in, const int* in_sizes, int n_in,
                              void* d_out, int out_size, void* d_ws, size_t ws_size,
                              hipStream_t stream)
{
    const float* x     = (const float*)d_in[0];
    const float* Win   = (const float*)d_in[1];
    const float* Wdw   = (const float*)d_in[2];
    const float* quant = (const float*)d_in[3];
    const float* Wout  = (const float*)d_in[4];
    float* out = (float*)d_out;

    // ws layout: WinH fp16 [0, 43520) ; WoutTH fp16 [43520, 65280) ; yr at 64 KiB.
    _Float16* WinH   = (_Float16*)d_ws;
    _Float16* WoutTH = (_Float16*)((char*)d_ws + 43520);
    _Float16* yrbuf  = (_Float16*)((char*)d_ws + 65536);

    const size_t perBatch = (size_t)C2 * NPIX * sizeof(_Float16);  // 44.56 MB
    const size_t avail = ws_size > 65536 ? ws_size - 65536 : 0;
    int nb = 1;
    if (avail >= 4 * perBatch)      nb = 4;
    else if (avail >= 2 * perBatch) nb = 2;

    kprep<<<128, 256, 0, stream>>>(Win, Wout, WinH, WoutTH);

    for (int b0 = 0; b0 < 4; b0 += nb) {
        dim3 grid(256, nb);
        kA<<<grid, 256, 0, stream>>>(x + (size_t)b0 * CIN * NPIX, WinH, quant, yrbuf);
        kB<<<grid, 256, 0, stream>>>(yrbuf, Wdw, WoutTH, out + (size_t)b0 * CIN * NPIX);
    }
}

// Round 4
// 551.949 us; speedup vs baseline: 2.5765x; 1.0719x over previous
//
#include <hip/hip_runtime.h>
#include <cmath>

#define HW   256
#define NPIX 65536       // 256*256
#define NP   65600       // padded channel stride for yr (64-entry zero pad)
#define CIN  64
#define C2   340
#define HID  170

typedef _Float16 f16x8 __attribute__((ext_vector_type(8)));
typedef float    f32x4 __attribute__((ext_vector_type(4)));

// Orthonormal DCT-II basis for n=8 as compile-time constants.
#define A0 0.35355339059327373f
#define A1 0.49039264020161522f
#define A2 0.46193976625564337f
#define A3 0.41573480615127262f
#define A4 0.35355339059327379f
#define A5 0.27778511650980114f
#define A6 0.19134171618254492f
#define A7 0.09754516100806417f

__device__ static constexpr float MD[8][8] = {
    { A0,  A0,  A0,  A0,  A0,  A0,  A0,  A0},
    { A1,  A3,  A5,  A7, -A7, -A5, -A3, -A1},
    { A2,  A6, -A6, -A2, -A2, -A6,  A6,  A2},
    { A3, -A7, -A1, -A5,  A5,  A1,  A7, -A3},
    { A4, -A4, -A4,  A4,  A4, -A4, -A4,  A4},
    { A5, -A1,  A7,  A3, -A3, -A7,  A1, -A5},
    { A6, -A2,  A2, -A6, -A6,  A2, -A2,  A6},
    { A7, -A5,  A3, -A1,  A1, -A3,  A5, -A7},
};

// ---------------------------------------------------------------------------
// Prep: WinH fp16 [352][64] (rows >=340 zero), WoutKH fp16 [64][192]
// (WoutKH[o][h] = Wout[o][h], h>=170 zero).
// ---------------------------------------------------------------------------
__global__ __launch_bounds__(256) void kprep(const float* __restrict__ Win,
                                             const float* __restrict__ Wout,
                                             _Float16* __restrict__ WinH,
                                             _Float16* __restrict__ WoutKH)
{
    const int i = blockIdx.x * 256 + threadIdx.x;
    if (i < 352 * 64) WinH[i] = (i < C2 * 64) ? (_Float16)Win[i] : (_Float16)0.f;
    if (i < 64 * 192) {
        const int o = i / 192, h = i - o * 192;
        WoutKH[i] = (h < HID) ? (_Float16)Wout[o * HID + h] : (_Float16)0.f;
    }
}

// ---------------------------------------------------------------------------
// Kernel A: project_in via MFMA + VALU DCT/quant/IDCT -> yr fp16 (padded NP).
// Block 256 (4 waves), tile 16x16 px, 11 chunks of 32 oc.
// ---------------------------------------------------------------------------
__global__ __launch_bounds__(256) void kA(
    const float* __restrict__ x,        // [nb][64][256][256]
    const _Float16* __restrict__ WinH,  // [352][64] fp16 (zero-padded)
    const float* __restrict__ quant,    // [340][8][8]
    _Float16* __restrict__ yr)          // [nb][340][NP] fp16
{
    const int tid  = threadIdx.x;
    const int tile = blockIdx.x;
    const int bb   = blockIdx.y;
    const int ty = tile >> 4, tx = tile & 15;
    const int r  = tid >> 4,  c  = tid & 15;
    const int wv = tid >> 6;
    const int l15 = tid & 15, quad = (tid & 63) >> 4;

    __shared__ union {
        _Float16 ash[256 * 64];         // 32768 B (prologue only)
        float    csh[32 * 264];         // 33792 B (chunk loop)
    } shm;

    // Zero yr's per-channel pad region for this batch (tile 0 blocks only).
    if (tile == 0) {
        const f16x8 z = {(_Float16)0.f,(_Float16)0.f,(_Float16)0.f,(_Float16)0.f,
                         (_Float16)0.f,(_Float16)0.f,(_Float16)0.f,(_Float16)0.f};
#pragma unroll 1
        for (int it = 0; it < 11; ++it) {
            const int idx = tid + it * 256;            // 2720 groups of 8
            if (idx < C2 * 8) {
                const int oc = idx >> 3, sub = idx & 7;
                *(f16x8*)&yr[(size_t)(bb * C2 + oc) * NP + NPIX + sub * 8] = z;
            }
        }
    }

    // ---- Stage x tile -> LDS fp16 (XOR swizzle on 8-elt units) ----
    const float* xp = x + (size_t)bb * (CIN * NPIX) + (ty * 16 + r) * HW + (tx * 16 + c);
    const int sw = tid & 7;
#pragma unroll
    for (int u = 0; u < 8; ++u) {
        union { _Float16 h[8]; f16x8 v; } pk;
#pragma unroll
        for (int j = 0; j < 8; ++j) pk.h[j] = (_Float16)xp[(size_t)(u * 8 + j) * NPIX];
        *(f16x8*)&shm.ash[tid * 64 + ((u ^ sw) * 8)] = pk.v;
    }
    __syncthreads();

    // ---- Hoist A fragments into registers (reused by every chunk) ----
    f16x8 af0[4], af1[4];
#pragma unroll
    for (int tt = 0; tt < 4; ++tt) {
        const int apx = (wv * 4 + tt) * 16 + l15;
        const int asw = apx & 7;
        af0[tt] = *(const f16x8*)&shm.ash[apx * 64 + ((quad ^ asw) * 8)];
        af1[tt] = *(const f16x8*)&shm.ash[apx * 64 + (((4 + quad) ^ asw) * 8)];
    }
    __syncthreads();   // Ash dead; csh may now be written

    // DCT-role indices
    const int ch  = tid >> 5;             // 0..7
    const int pat = (tid >> 3) & 3;       // 0..3
    const int lan = tid & 7;              // 0..7
    const int pr8 = (pat >> 1) * 8;
    const int pc8 = (pat & 1) * 8;

#pragma unroll 1
    for (int sc = 0; sc < 11; ++sc) {
        const int oc0 = sc * 32;

        // ---- MFMA projection: 32 oc (2 groups of 16) ----
#pragma unroll
        for (int g2 = 0; g2 < 2; ++g2) {
            const int ocb = oc0 + g2 * 16 + l15;           // WinH zero-padded
            const f16x8 b0 = *(const f16x8*)(WinH + ocb * 64 + quad * 8);
            const f16x8 b1 = *(const f16x8*)(WinH + ocb * 64 + 32 + quad * 8);
#pragma unroll
            for (int tt = 0; tt < 4; ++tt) {
                f32x4 acc = {0.f, 0.f, 0.f, 0.f};
                acc = __builtin_amdgcn_mfma_f32_16x16x32_f16(af0[tt], b0, acc, 0, 0, 0);
                acc = __builtin_amdgcn_mfma_f32_16x16x32_f16(af1[tt], b1, acc, 0, 0, 0);
                // D: col=l15 (oc), row=quad*4+reg (px) -> 4 consecutive px: b128
                *(f32x4*)&shm.csh[(g2 * 16 + l15) * 264 + (wv * 4 + tt) * 16 + quad * 4] = acc;
            }
        }
        __syncthreads();

        // ---- R1 (rows): out[j] = sum_q v[q]*MD[j][q], in place, b128 IO ----
#pragma unroll
        for (int di = 0; di < 4; ++di) {
            float* row = &shm.csh[(ch + 8 * di) * 264 + (pr8 + lan) * 16 + pc8];
            float v[8], o[8];
            *(f32x4*)&v[0] = *(const f32x4*)row;
            *(f32x4*)&v[4] = *(const f32x4*)(row + 4);
#pragma unroll
            for (int j = 0; j < 8; ++j) {
                float s = v[0] * MD[j][0];
#pragma unroll
                for (int q = 1; q < 8; ++q) s = fmaf(v[q], MD[j][q], s);
                o[j] = s;
            }
            *(f32x4*)row       = *(const f32x4*)&o[0];
            *(f32x4*)(row + 4) = *(const f32x4*)&o[4];
        }
        __syncthreads();

        // ---- Cols: d = M v ; d *= quant ; e = M^T d, in place ----
#pragma unroll
        for (int di = 0; di < 4; ++di) {
            const int ocl = ch + 8 * di;
            float* colp = &shm.csh[ocl * 264 + pr8 * 16 + pc8 + lan];
            float v[8], d[8], e[8];
#pragma unroll
            for (int i = 0; i < 8; ++i) v[i] = colp[i * 16];
            int ocq = oc0 + ocl; if (ocq > C2 - 1) ocq = C2 - 1;
            const float* qp = quant + ocq * 64 + lan;
#pragma unroll
            for (int i = 0; i < 8; ++i) {
                float s = v[0] * MD[i][0];
#pragma unroll
                for (int p = 1; p < 8; ++p) s = fmaf(v[p], MD[i][p], s);
                d[i] = s * qp[i * 8];
            }
#pragma unroll
            for (int p = 0; p < 8; ++p) {
                float s = d[0] * MD[0][p];
#pragma unroll
                for (int i = 1; i < 8; ++i) s = fmaf(d[i], MD[i][p], s);
                e[p] = s;
            }
#pragma unroll
            for (int i = 0; i < 8; ++i) colp[i * 16] = e[i];
        }
        __syncthreads();

        // ---- R2 (rows): out[q] = sum_j v[j]*MD[j][q] -> global fp16 ----
#pragma unroll
        for (int di = 0; di < 4; ++di) {
            const int oc = oc0 + ch + 8 * di;
            const float* row = &shm.csh[(ch + 8 * di) * 264 + (pr8 + lan) * 16 + pc8];
            float v[8];
            *(f32x4*)&v[0] = *(const f32x4*)row;
            *(f32x4*)&v[4] = *(const f32x4*)(row + 4);
            union { _Float16 h[8]; f16x8 f; } u;
#pragma unroll
            for (int q = 0; q < 8; ++q) {
                float s = v[0] * MD[0][q];
#pragma unroll
                for (int j = 1; j < 8; ++j) s = fmaf(v[j], MD[j][q], s);
                u.h[q] = (_Float16)s;
            }
            if (oc < C2) {
                f16x8* dst = (f16x8*)(yr + (size_t)(bb * C2 + oc) * NP
                                      + (ty * 16 + pr8 + lan) * HW + tx * 16 + pc8);
                *dst = u.f;
            }
        }
        __syncthreads();
    }
}

// ---------------------------------------------------------------------------
// Kernel B: depthwise 3x3 + exact gelu gate (VALU) + project_out (MFMA).
// Block 256, tile 64x4 px.  6 chunks of 32 h; g staged fp16 in LDS.
// Borders read yr's zeroed per-channel pad (branch-free inner loop).
// ---------------------------------------------------------------------------
__global__ __launch_bounds__(256) void kB(
    const _Float16* __restrict__ yr,      // [nb][340][NP] fp16
    const float* __restrict__ Wdw,        // [340][9]
    const _Float16* __restrict__ WoutKH,  // [64][192] fp16 (zero-padded)
    float* __restrict__ out)              // [nb][64][256][256]
{
    const int tid = threadIdx.x;
    const int bb  = blockIdx.y;
    const int tyb = blockIdx.x >> 2, txb = blockIdx.x & 3;
    const int r = tid >> 6, c = tid & 63;
    const int y0 = tyb * 4 + r, x0 = txb * 64 + c;
    const int wv = tid >> 6;
    const int l15 = tid & 15, quad = (tid & 63) >> 4;

    __shared__ union {
        _Float16 g[256 * 32];    // 16384 B: g tile for one 32-h chunk
        float    t[16 * 257];    // 16448 B: epilogue transpose
    } shm;

    const _Float16* ybase = yr + (size_t)bb * C2 * NP;
    const int base0 = y0 * HW + x0;

    // Precompute 9 tap offsets; OOB taps redirect into the zeroed pad.
    int off[9];
    {
        const int padoff = NPIX + (tid & 63) - base0;
        int k = 0;
#pragma unroll
        for (int dy = -1; dy <= 1; ++dy)
#pragma unroll
            for (int dx = -1; dx <= 1; ++dx, ++k) {
                const int gy = y0 + dy, gx = x0 + dx;
                const bool ok = ((unsigned)gy < (unsigned)HW) && ((unsigned)gx < (unsigned)HW);
                off[k] = ok ? (dy * HW + dx) : padoff;
            }
    }

    f32x4 acc[4][4];   // [px-tile tt][oc-group]
#pragma unroll
    for (int a = 0; a < 4; ++a)
#pragma unroll
        for (int b = 0; b < 4; ++b) acc[a][b] = (f32x4){0.f, 0.f, 0.f, 0.f};

#pragma unroll 1
    for (int chunk = 0; chunk < 6; ++chunk) {
        const int h0 = chunk * 32;

        // ---- g for 32 channels -> LDS fp16 (XOR-swizzled 8-elt units) ----
#pragma unroll
        for (int u = 0; u < 4; ++u) {
            union { _Float16 h[8]; f16x8 v; } pk;
#pragma unroll
            for (int j = 0; j < 8; ++j) {
                const int h = h0 + u * 8 + j;
                float gg = 0.f;
                if (h < HID) {
                    const _Float16* p1 = ybase + (size_t)h * NP + base0;
                    const _Float16* p2 = p1 + (size_t)HID * NP;
                    const float* w1 = Wdw + h * 9;
                    const float* w2 = w1 + HID * 9;
                    float s1 = 0.f, s2 = 0.f;
#pragma unroll
                    for (int k = 0; k < 9; ++k) {
                        s1 = fmaf((float)p1[off[k]], w1[k], s1);
                        s2 = fmaf((float)p2[off[k]], w2[k], s2);
                    }
                    gg = 0.5f * s1 * (1.f + erff(s1 * 0.70710678118654752f)) * s2;
                }
                pk.h[j] = (_Float16)gg;
            }
            *(f16x8*)&shm.g[tid * 32 + ((u ^ (tid & 3)) * 8)] = pk.v;
        }
        __syncthreads();

        // ---- MFMA: acc[px, oc] += g[px, h32] * WoutKH[oc][h32] ----
#pragma unroll
        for (int tt = 0; tt < 4; ++tt) {
            const int apx = (wv * 4 + tt) * 16 + l15;
            const f16x8 a = *(const f16x8*)&shm.g[apx * 32 + ((quad ^ (apx & 3)) * 8)];
#pragma unroll
            for (int p = 0; p < 4; ++p) {
                const f16x8 b = *(const f16x8*)(WoutKH + (p * 16 + l15) * 192 + h0 + quad * 8);
                acc[tt][p] = __builtin_amdgcn_mfma_f32_16x16x32_f16(a, b, acc[tt][p], 0, 0, 0);
            }
        }
        __syncthreads();
    }

    // ---- Epilogue: LDS transpose -> coalesced stores (4 passes of 16 oc) ----
    float* ob = out + (size_t)bb * CIN * NPIX + base0;
#pragma unroll 1
    for (int p = 0; p < 4; ++p) {
#pragma unroll
        for (int tt = 0; tt < 4; ++tt) {
            const int px = (wv * 4 + tt) * 16 + quad * 4;
#pragma unroll
            for (int reg = 0; reg < 4; ++reg)
                shm.t[l15 * 257 + px + reg] = acc[tt][p][reg];
        }
        __syncthreads();
#pragma unroll
        for (int o2 = 0; o2 < 16; ++o2)
            ob[(size_t)(p * 16 + o2) * NPIX] = shm.t[o2 * 257 + tid];
        __syncthreads();
    }
}

extern "C" void kernel_launch(void* const* d_in, const int* in_sizes, int n_in,
                              void* d_out, int out_size, void* d_ws, size_t ws_size,
                              hipStream_t stream)
{
    const float* x     = (const float*)d_in[0];
    const float* Win   = (const float*)d_in[1];
    const float* Wdw   = (const float*)d_in[2];
    const float* quant = (const float*)d_in[3];
    const float* Wout  = (const float*)d_in[4];
    float* out = (float*)d_out;

    // ws: WinH [0,45056) ; WoutKH [45056,69632) ; yr at 69632 (16B aligned).
    _Float16* WinH   = (_Float16*)d_ws;
    _Float16* WoutKH = (_Float16*)((char*)d_ws + 45056);
    _Float16* yrbuf  = (_Float16*)((char*)d_ws + 69632);

    const size_t perBatch = (size_t)C2 * NP * sizeof(_Float16);  // 44.6 MB
    const size_t head = 69632;
    const size_t avail = ws_size > head ? ws_size - head : 0;
    int nb = 1;
    if (avail >= 4 * perBatch)      nb = 4;
    else if (avail >= 2 * perBatch) nb = 2;

    kprep<<<88, 256, 0, stream>>>(Win, Wout, WinH, WoutKH);

    for (int b0 = 0; b0 < 4; b0 += nb) {
        dim3 grid(256, nb);
        kA<<<grid, 256, 0, stream>>>(x + (size_t)b0 * CIN * NPIX, WinH, quant, yrbuf);
        kB<<<grid, 256, 0, stream>>>(yrbuf, Wdw, WoutKH, out + (size_t)b0 * CIN * NPIX);
    }
}